// Round 1
// baseline (1171.376 us; speedup 1.0000x reference)
//
#include <hip/hip_runtime.h>
#include <stdint.h>

typedef __attribute__((ext_vector_type(8))) short bf16x8;
typedef __attribute__((ext_vector_type(4))) float f32x4;
typedef __attribute__((ext_vector_type(4))) int i32x4;

__device__ __forceinline__ unsigned short f2bf(float f) {
    unsigned int u = __float_as_uint(f);
    u += 0x7FFFu + ((u >> 16) & 1u);
    return (unsigned short)(u >> 16);
}
__device__ __forceinline__ float bf2f(unsigned short s) {
    return __uint_as_float(((unsigned int)s) << 16);
}

// ---------------- CSR build ----------------
__global__ __launch_bounds__(256) void k_count(const int* __restrict__ dst, int E,
                                               int* __restrict__ cnt) {
    int i = blockIdx.x * blockDim.x + threadIdx.x;
    if (i < E) atomicAdd(&cnt[dst[i]], 1);
}

__global__ __launch_bounds__(256) void k_dinv(const int* __restrict__ cnt,
                                              float* __restrict__ dinv, int n) {
    int i = blockIdx.x * blockDim.x + threadIdx.x;
    if (i < n) dinv[i] = rsqrtf((float)cnt[i] + 1.0f);  // +1 self-loop
}

__global__ __launch_bounds__(512) void k_scanA(const int* __restrict__ cnt,
                                               int* __restrict__ rowp,
                                               int* __restrict__ part, int n) {
    __shared__ int sh[512];
    int t = threadIdx.x, i = blockIdx.x * 512 + t;
    int v = (i < n) ? cnt[i] : 0;
    sh[t] = v;
    __syncthreads();
    for (int off = 1; off < 512; off <<= 1) {
        int x = (t >= off) ? sh[t - off] : 0;
        __syncthreads();
        sh[t] += x;
        __syncthreads();
    }
    if (i < n) rowp[i] = sh[t] - v;  // exclusive
    if (t == 511) part[blockIdx.x] = sh[511];
}

__global__ void k_scanB(int* __restrict__ part, int nb) {
    if (threadIdx.x == 0) {
        int s = 0;
        for (int i = 0; i < nb; i++) { int v = part[i]; part[i] = s; s += v; }
    }
}

__global__ __launch_bounds__(256) void k_scanC(int* __restrict__ rowp,
                                               int* __restrict__ cursor,
                                               const int* __restrict__ part, int n, int E) {
    int i = blockIdx.x * blockDim.x + threadIdx.x;
    if (i < n) {
        int r = rowp[i] + part[i >> 9];
        rowp[i] = r;
        cursor[i] = r;
    }
    if (i == n) rowp[n] = E;
}

__global__ __launch_bounds__(256) void k_scatter(const int* __restrict__ src,
                                                 const int* __restrict__ dst, int E,
                                                 int* __restrict__ cursor,
                                                 int* __restrict__ col) {
    int i = blockIdx.x * blockDim.x + threadIdx.x;
    if (i < E) {
        int p = atomicAdd(&cursor[dst[i]], 1);
        col[p] = src[i];
    }
}

// ---------------- dtype conversion ----------------
__global__ __launch_bounds__(256) void k_cvt_x(const float4* __restrict__ x,
                                               ushort4* __restrict__ xb, int n4) {
    int i = blockIdx.x * blockDim.x + threadIdx.x;
    if (i < n4) {
        float4 v = x[i];
        ushort4 o;
        o.x = f2bf(v.x); o.y = f2bf(v.y); o.z = f2bf(v.z); o.w = f2bf(v.w);
        xb[i] = o;
    }
}

// W [K][N] f32 -> Wt [N][ldt] bf16 (transposed)
__global__ __launch_bounds__(256) void k_cvt_wt(const float* __restrict__ W,
                                                short* __restrict__ Wt, int K, int N, int ldt) {
    int i = blockIdx.x * blockDim.x + threadIdx.x;
    if (i < K * N) {
        int k = i / N, c = i - k * N;
        Wt[(size_t)c * ldt + k] = (short)f2bf(W[i]);
    }
}

// ---------------- bf16 MFMA GEMM, NT layout (A [M][K], Bt [N][K]) ----------------
// Epilogue: out[row][c] = bf16(acc * dinv[row]), c < ncols. BM=128, BN=32*NJ, BK=32.
template <int NJ>
__global__ __launch_bounds__(256) void k_gemm_bt(const short* __restrict__ A,
                                                 const short* __restrict__ Bt,
                                                 const float* __restrict__ dinv,
                                                 short* __restrict__ outp,
                                                 int M, int K, int ldo, int ncols) {
    constexpr int BN = 32 * NJ;
    __shared__ __align__(16) short As[128 * 32];
    __shared__ __align__(16) short Bs[BN * 32];
    const int tid = threadIdx.x;
    const int m0 = blockIdx.x * 128;
    const int n0 = blockIdx.y * BN;
    const int w = tid >> 6, lane = tid & 63;
    const int quad = lane >> 4, l16 = lane & 15;
    const int mbase = (w >> 1) * 64, nbase = (w & 1) * (NJ * 16);

    f32x4 acc[4][NJ];
#pragma unroll
    for (int i = 0; i < 4; i++)
#pragma unroll
        for (int j = 0; j < NJ; j++) acc[i][j] = (f32x4){0.f, 0.f, 0.f, 0.f};

    for (int k0 = 0; k0 < K; k0 += 32) {
#pragma unroll
        for (int s = tid; s < 512; s += 256) {  // A tile: 128 rows x 64B
            int r = s >> 2, seg = s & 3;
            int gr = m0 + r;
            if (gr >= M) gr = M - 1;
            i32x4 v = *(const i32x4*)(A + (size_t)gr * K + k0 + seg * 8);
            *(i32x4*)(As + r * 32 + seg * 8) = v;
        }
#pragma unroll
        for (int s = tid; s < BN * 4; s += 256) {  // B tile: BN rows x 64B
            int r = s >> 2, seg = s & 3;
            i32x4 v = *(const i32x4*)(Bt + (size_t)(n0 + r) * K + k0 + seg * 8);
            *(i32x4*)(Bs + r * 32 + seg * 8) = v;
        }
        __syncthreads();
        bf16x8 af[4], bfr[NJ];
#pragma unroll
        for (int i = 0; i < 4; i++)
            af[i] = *(const bf16x8*)(As + (mbase + i * 16 + l16) * 32 + quad * 8);
#pragma unroll
        for (int j = 0; j < NJ; j++)
            bfr[j] = *(const bf16x8*)(Bs + (nbase + j * 16 + l16) * 32 + quad * 8);
#pragma unroll
        for (int i = 0; i < 4; i++)
#pragma unroll
            for (int j = 0; j < NJ; j++)
                acc[i][j] = __builtin_amdgcn_mfma_f32_16x16x32_bf16(af[i], bfr[j], acc[i][j], 0, 0, 0);
        __syncthreads();
    }

#pragma unroll
    for (int i = 0; i < 4; i++) {
#pragma unroll
        for (int r = 0; r < 4; r++) {
            int row = m0 + mbase + i * 16 + quad * 4 + r;
            if (row < M) {
                float dv = dinv[row];
#pragma unroll
                for (int j = 0; j < NJ; j++) {
                    int c = n0 + nbase + j * 16 + l16;
                    if (c < ncols)
                        outp[(size_t)row * ldo + c] = (short)f2bf(acc[i][j][r] * dv);
                }
            }
        }
    }
}

// ---------------- aggregation, layer 1 (256 feats), fused bias+relu ----------------
__global__ __launch_bounds__(256) void k_agg1(const short* __restrict__ h1p,
                                              const int* __restrict__ rowp,
                                              const int* __restrict__ col,
                                              const float* __restrict__ dinv,
                                              const float* __restrict__ b1,
                                              short* __restrict__ h2, int n) {
    const int w = threadIdx.x >> 6, lane = threadIdx.x & 63;
    const int v = blockIdx.x * 4 + w;
    if (v >= n) return;
    const int c4 = lane * 4;
    float a0, a1, a2, a3;
    {
        ushort4 u = *(const ushort4*)(h1p + (size_t)v * 256 + c4);  // self-loop
        a0 = bf2f(u.x); a1 = bf2f(u.y); a2 = bf2f(u.z); a3 = bf2f(u.w);
    }
    const int e0 = rowp[v], e1 = rowp[v + 1];
    int e = e0;
    for (; e + 4 <= e1; e += 4) {
        int sa = col[e], sb = col[e + 1], sc = col[e + 2], sd = col[e + 3];
        ushort4 ua = *(const ushort4*)(h1p + (size_t)sa * 256 + c4);
        ushort4 ub = *(const ushort4*)(h1p + (size_t)sb * 256 + c4);
        ushort4 uc = *(const ushort4*)(h1p + (size_t)sc * 256 + c4);
        ushort4 ud = *(const ushort4*)(h1p + (size_t)sd * 256 + c4);
        a0 += bf2f(ua.x) + bf2f(ub.x) + bf2f(uc.x) + bf2f(ud.x);
        a1 += bf2f(ua.y) + bf2f(ub.y) + bf2f(uc.y) + bf2f(ud.y);
        a2 += bf2f(ua.z) + bf2f(ub.z) + bf2f(uc.z) + bf2f(ud.z);
        a3 += bf2f(ua.w) + bf2f(ub.w) + bf2f(uc.w) + bf2f(ud.w);
    }
    for (; e < e1; e++) {
        int s = col[e];
        ushort4 u = *(const ushort4*)(h1p + (size_t)s * 256 + c4);
        a0 += bf2f(u.x); a1 += bf2f(u.y); a2 += bf2f(u.z); a3 += bf2f(u.w);
    }
    const float dv = dinv[v];
    float r0 = fmaxf(fmaf(dv, a0, b1[c4 + 0]), 0.f);
    float r1 = fmaxf(fmaf(dv, a1, b1[c4 + 1]), 0.f);
    float r2 = fmaxf(fmaf(dv, a2, b1[c4 + 2]), 0.f);
    float r3 = fmaxf(fmaf(dv, a3, b1[c4 + 3]), 0.f);
    ushort4 o;
    o.x = f2bf(r0); o.y = f2bf(r1); o.z = f2bf(r2); o.w = f2bf(r3);
    *(ushort4*)(h2 + (size_t)v * 256 + c4) = o;
}

// ---------------- aggregation, layer 2 (40 feats) + bias + log_softmax ----------------
__global__ __launch_bounds__(256) void k_agg2(const short* __restrict__ zp,
                                              const int* __restrict__ rowp,
                                              const int* __restrict__ col,
                                              const float* __restrict__ dinv,
                                              const float* __restrict__ b2,
                                              float* __restrict__ out, int n) {
    const int w = threadIdx.x >> 6, lane = threadIdx.x & 63;
    const int v = blockIdx.x * 4 + w;
    if (v >= n) return;
    const bool act = lane < 40;
    const int li = act ? lane : 0;
    float acc = act ? bf2f((unsigned short)zp[(size_t)v * 40 + li]) : 0.f;  // self-loop
    const int e0 = rowp[v], e1 = rowp[v + 1];
    int e = e0;
    for (; e + 4 <= e1; e += 4) {
        int sa = col[e], sb = col[e + 1], sc = col[e + 2], sd = col[e + 3];
        float fa = bf2f((unsigned short)zp[(size_t)sa * 40 + li]);
        float fb = bf2f((unsigned short)zp[(size_t)sb * 40 + li]);
        float fc = bf2f((unsigned short)zp[(size_t)sc * 40 + li]);
        float fd = bf2f((unsigned short)zp[(size_t)sd * 40 + li]);
        if (act) acc += fa + fb + fc + fd;
    }
    for (; e < e1; e++) {
        float f = bf2f((unsigned short)zp[(size_t)col[e] * 40 + li]);
        if (act) acc += f;
    }
    float logit = act ? fmaf(dinv[v], acc, b2[li]) : -1e30f;
    float m = logit;
    for (int off = 32; off; off >>= 1) m = fmaxf(m, __shfl_xor(m, off));
    float ex = act ? expf(logit - m) : 0.f;
    float ssum = ex;
    for (int off = 32; off; off >>= 1) ssum += __shfl_xor(ssum, off);
    if (act) out[(size_t)v * 40 + lane] = logit - m - logf(ssum);
}

extern "C" void kernel_launch(void* const* d_in, const int* in_sizes, int n_in,
                              void* d_out, int out_size, void* d_ws, size_t ws_size,
                              hipStream_t stream) {
    const float* x  = (const float*)d_in[0];
    const float* W1 = (const float*)d_in[1];
    const float* b1 = (const float*)d_in[2];
    const float* W2 = (const float*)d_in[3];
    const float* b2 = (const float*)d_in[4];
    const int*   ei = (const int*)d_in[5];
    float* out = (float*)d_out;

    const int FIN = 512, H = 256, C = 40;
    const int n = in_sizes[0] / FIN;   // 100000
    const int E = in_sizes[5] / 2;     // 3200000

    auto align_up = [](size_t v) { return (v + 255) & ~(size_t)255; };
    char* base = (char*)d_ws;
    size_t off = 0;
    short* x_bf = (short*)(base + off); off += align_up((size_t)n * FIN * 2);  // reused as h2
    short* h1p  = (short*)(base + off); off += align_up((size_t)n * H * 2);    // reused as zp
    float* dinv = (float*)(base + off); off += align_up((size_t)n * 4);
    int* cnt    = (int*)(base + off);   off += align_up((size_t)n * 4);
    int* rowp   = (int*)(base + off);   off += align_up((size_t)(n + 1) * 4);
    int* cursor = (int*)(base + off);   off += align_up((size_t)n * 4);
    int* colarr = (int*)(base + off);   off += align_up((size_t)E * 4);
    short* W1t  = (short*)(base + off); off += align_up((size_t)H * FIN * 2);
    short* W2t  = (short*)(base + off); off += align_up((size_t)64 * H * 2);
    int* part   = (int*)(base + off);   off += align_up(1024);
    short* h2 = x_bf;   // layer-1 output (after x_bf consumed by gemm1)
    short* zp = h1p;    // layer-2 scaled logits (after h1p consumed by agg1)

    const int* srcp = ei;
    const int* dstp = ei + E;

    hipMemsetAsync(cnt, 0, (size_t)n * 4, stream);
    hipMemsetAsync(W2t, 0, (size_t)64 * H * 2, stream);

    k_count<<<(E + 255) / 256, 256, 0, stream>>>(dstp, E, cnt);
    k_dinv<<<(n + 255) / 256, 256, 0, stream>>>(cnt, dinv, n);
    int nb = (n + 511) / 512;
    k_scanA<<<nb, 512, 0, stream>>>(cnt, rowp, part, n);
    k_scanB<<<1, 64, 0, stream>>>(part, nb);
    k_scanC<<<(n + 256) / 256, 256, 0, stream>>>(rowp, cursor, part, n, E);
    k_scatter<<<(E + 255) / 256, 256, 0, stream>>>(srcp, dstp, E, cursor, colarr);

    int n4 = n * (FIN / 4);
    k_cvt_x<<<(n4 + 255) / 256, 256, 0, stream>>>((const float4*)x, (ushort4*)x_bf, n4);
    k_cvt_wt<<<(FIN * H + 255) / 256, 256, 0, stream>>>(W1, W1t, FIN, H, FIN);
    k_cvt_wt<<<(H * C + 255) / 256, 256, 0, stream>>>(W2, W2t, H, C, H);

    dim3 g1((n + 127) / 128, H / 128);
    k_gemm_bt<4><<<g1, 256, 0, stream>>>(x_bf, W1t, dinv, h1p, n, FIN, H, H);
    k_agg1<<<(n + 3) / 4, 256, 0, stream>>>(h1p, rowp, colarr, dinv, b1, h2, n);
    dim3 g2((n + 127) / 128, 1);
    k_gemm_bt<2><<<g2, 256, 0, stream>>>(h2, W2t, dinv, zp, n, H, C, C);
    k_agg2<<<(n + 3) / 4, 256, 0, stream>>>(zp, rowp, colarr, dinv, b2, out, n);
}

// Round 2
// 872.123 us; speedup vs baseline: 1.3431x; 1.3431x over previous
//
#include <hip/hip_runtime.h>
#include <stdint.h>

typedef __attribute__((ext_vector_type(8))) short bf16x8;
typedef __attribute__((ext_vector_type(4))) float f32x4;
typedef __attribute__((ext_vector_type(4))) int i32x4;

__device__ __forceinline__ unsigned short f2bf(float f) {
    unsigned int u = __float_as_uint(f);
    u += 0x7FFFu + ((u >> 16) & 1u);
    return (unsigned short)(u >> 16);
}
__device__ __forceinline__ float bf2f(unsigned short s) {
    return __uint_as_float(((unsigned int)s) << 16);
}

// ---------------- bucketed CSR build ----------------
// Bucket = 128 consecutive dst nodes (dst>>7). nbuck = ceil(n/128) = 782 for n=100000.
// Packed edge entry: (dst&127)<<20 | src   (src < 2^17 fits in 20 bits)

// Pass 1: global bucket histogram via per-block LDS hist (writes L2-hot, no 4B sprays)
__global__ __launch_bounds__(256) void k_bhist(const int* __restrict__ dst, int E,
                                               int* __restrict__ bcnt, int nbuck) {
    __shared__ int lh[1024];
    for (int i = threadIdx.x; i < nbuck; i += 256) lh[i] = 0;
    __syncthreads();
    for (int i = blockIdx.x * 256 + threadIdx.x; i < E; i += gridDim.x * 256)
        atomicAdd(&lh[dst[i] >> 7], 1);
    __syncthreads();
    for (int i = threadIdx.x; i < nbuck; i += 256) {
        int c = lh[i];
        if (c) atomicAdd(&bcnt[i], c);
    }
}

// Pass 2: exclusive scan of bucket counts -> bbase[0..nbuck], init bcur. nbuck <= 1023.
__global__ __launch_bounds__(1024) void k_bscan(const int* __restrict__ bcnt,
                                                int* __restrict__ bbase,
                                                int* __restrict__ bcur, int nbuck) {
    __shared__ int sh[1024];
    int t = threadIdx.x;
    int v = (t < nbuck) ? bcnt[t] : 0;
    sh[t] = v;
    __syncthreads();
    for (int off = 1; off < 1024; off <<= 1) {
        int x = (t >= off) ? sh[t - off] : 0;
        __syncthreads();
        sh[t] += x;
        __syncthreads();
    }
    if (t < nbuck) {
        int b = sh[t] - v;
        bbase[t] = b;
        bcur[t] = b;
    }
    if (t == nbuck) bbase[t] = sh[nbuck - 1];  // = E
}

// Pass 3: scatter packed edges into bucket regions. Per-block LDS hist -> one global
// reserve per (block,bucket) -> writes are ~80B runs inside L2-hot 16KB windows.
__global__ __launch_bounds__(256) void k_bscatter(const int* __restrict__ src,
                                                  const int* __restrict__ dst, int E,
                                                  int* __restrict__ bcur,
                                                  int* __restrict__ packed, int nbuck) {
    __shared__ int lh[1024];    // local count, then global base
    __shared__ int lcur[1024];
    const int CH = 8192;
    int e0 = blockIdx.x * CH;
    int e1 = min(E, e0 + CH);
    for (int i = threadIdx.x; i < nbuck; i += 256) lh[i] = 0;
    __syncthreads();
    for (int i = e0 + threadIdx.x; i < e1; i += 256) atomicAdd(&lh[dst[i] >> 7], 1);
    __syncthreads();
    for (int i = threadIdx.x; i < nbuck; i += 256) {
        int c = lh[i];
        lh[i] = c ? atomicAdd(&bcur[i], c) : 0;
        lcur[i] = 0;
    }
    __syncthreads();
    for (int i = e0 + threadIdx.x; i < e1; i += 256) {
        int d = dst[i], s = src[i];
        int b = d >> 7;
        int p = lh[b] + atomicAdd(&lcur[b], 1);
        packed[p] = ((d & 127) << 20) | s;
    }
}

// Pass 4: one block per bucket: hist dstlow -> scan -> rowp/dinv -> final col scatter
// (reads/writes confined to this bucket's ~16KB region, L2-resident).
__global__ __launch_bounds__(256) void k_bcsr(const int* __restrict__ packed,
                                              const int* __restrict__ bbase,
                                              int* __restrict__ rowp,
                                              int* __restrict__ col,
                                              float* __restrict__ dinv,
                                              int n, int E) {
    __shared__ int lh[128], lsc[128], lcur[128];
    const int b = blockIdx.x;
    const int base = bbase[b];
    const int cnt = bbase[b + 1] - base;
    const int t = threadIdx.x;
    if (t < 128) lh[t] = 0;
    __syncthreads();
    for (int i = t; i < cnt; i += 256) atomicAdd(&lh[packed[base + i] >> 20], 1);
    __syncthreads();
    if (t < 128) lsc[t] = lh[t];
    __syncthreads();
    for (int off = 1; off < 128; off <<= 1) {
        int x = (t < 128 && t >= off) ? lsc[t - off] : 0;
        __syncthreads();
        if (t < 128) lsc[t] += x;
        __syncthreads();
    }
    if (t < 128) {
        int excl = lsc[t] - lh[t];
        lcur[t] = excl;
        int v = (b << 7) + t;
        if (v < n) {
            rowp[v] = base + excl;
            dinv[v] = rsqrtf((float)lh[t] + 1.0f);  // +1 self-loop
        }
    }
    if (b == 0 && t == 0) rowp[n] = E;
    __syncthreads();
    for (int i = t; i < cnt; i += 256) {
        int pk = packed[base + i];
        int d = pk >> 20;
        int p = base + atomicAdd(&lcur[d], 1);
        col[p] = pk & 0xFFFFF;
    }
}

// ---------------- dtype conversion ----------------
__global__ __launch_bounds__(256) void k_cvt_x(const float4* __restrict__ x,
                                               ushort4* __restrict__ xb, int n4) {
    int i = blockIdx.x * blockDim.x + threadIdx.x;
    if (i < n4) {
        float4 v = x[i];
        ushort4 o;
        o.x = f2bf(v.x); o.y = f2bf(v.y); o.z = f2bf(v.z); o.w = f2bf(v.w);
        xb[i] = o;
    }
}

// W [K][N] f32 -> Wt [N][ldt] bf16 (transposed)
__global__ __launch_bounds__(256) void k_cvt_wt(const float* __restrict__ W,
                                                short* __restrict__ Wt, int K, int N, int ldt) {
    int i = blockIdx.x * blockDim.x + threadIdx.x;
    if (i < K * N) {
        int k = i / N, c = i - k * N;
        Wt[(size_t)c * ldt + k] = (short)f2bf(W[i]);
    }
}

// ---------------- bf16 MFMA GEMM, NT layout (A [M][K], Bt [N][K]) ----------------
// Epilogue: out[row][c] = bf16(acc * dinv[row]), c < ncols. BM=128, BN=32*NJ, BK=32.
template <int NJ>
__global__ __launch_bounds__(256) void k_gemm_bt(const short* __restrict__ A,
                                                 const short* __restrict__ Bt,
                                                 const float* __restrict__ dinv,
                                                 short* __restrict__ outp,
                                                 int M, int K, int ldo, int ncols) {
    constexpr int BN = 32 * NJ;
    __shared__ __align__(16) short As[128 * 32];
    __shared__ __align__(16) short Bs[BN * 32];
    const int tid = threadIdx.x;
    const int m0 = blockIdx.x * 128;
    const int n0 = blockIdx.y * BN;
    const int w = tid >> 6, lane = tid & 63;
    const int quad = lane >> 4, l16 = lane & 15;
    const int mbase = (w >> 1) * 64, nbase = (w & 1) * (NJ * 16);

    f32x4 acc[4][NJ];
#pragma unroll
    for (int i = 0; i < 4; i++)
#pragma unroll
        for (int j = 0; j < NJ; j++) acc[i][j] = (f32x4){0.f, 0.f, 0.f, 0.f};

    for (int k0 = 0; k0 < K; k0 += 32) {
#pragma unroll
        for (int s = tid; s < 512; s += 256) {  // A tile: 128 rows x 64B
            int r = s >> 2, seg = s & 3;
            int gr = m0 + r;
            if (gr >= M) gr = M - 1;
            i32x4 v = *(const i32x4*)(A + (size_t)gr * K + k0 + seg * 8);
            *(i32x4*)(As + r * 32 + seg * 8) = v;
        }
#pragma unroll
        for (int s = tid; s < BN * 4; s += 256) {  // B tile: BN rows x 64B
            int r = s >> 2, seg = s & 3;
            i32x4 v = *(const i32x4*)(Bt + (size_t)(n0 + r) * K + k0 + seg * 8);
            *(i32x4*)(Bs + r * 32 + seg * 8) = v;
        }
        __syncthreads();
        bf16x8 af[4], bfr[NJ];
#pragma unroll
        for (int i = 0; i < 4; i++)
            af[i] = *(const bf16x8*)(As + (mbase + i * 16 + l16) * 32 + quad * 8);
#pragma unroll
        for (int j = 0; j < NJ; j++)
            bfr[j] = *(const bf16x8*)(Bs + (nbase + j * 16 + l16) * 32 + quad * 8);
#pragma unroll
        for (int i = 0; i < 4; i++)
#pragma unroll
            for (int j = 0; j < NJ; j++)
                acc[i][j] = __builtin_amdgcn_mfma_f32_16x16x32_bf16(af[i], bfr[j], acc[i][j], 0, 0, 0);
        __syncthreads();
    }

#pragma unroll
    for (int i = 0; i < 4; i++) {
#pragma unroll
        for (int r = 0; r < 4; r++) {
            int row = m0 + mbase + i * 16 + quad * 4 + r;
            if (row < M) {
                float dv = dinv[row];
#pragma unroll
                for (int j = 0; j < NJ; j++) {
                    int c = n0 + nbase + j * 16 + l16;
                    if (c < ncols)
                        outp[(size_t)row * ldo + c] = (short)f2bf(acc[i][j][r] * dv);
                }
            }
        }
    }
}

// ---------------- aggregation, layer 1 (256 feats), fused bias+relu ----------------
__global__ __launch_bounds__(256) void k_agg1(const short* __restrict__ h1p,
                                              const int* __restrict__ rowp,
                                              const int* __restrict__ col,
                                              const float* __restrict__ dinv,
                                              const float* __restrict__ b1,
                                              short* __restrict__ h2, int n) {
    const int w = threadIdx.x >> 6, lane = threadIdx.x & 63;
    const int v = blockIdx.x * 4 + w;
    if (v >= n) return;
    const int c4 = lane * 4;
    float a0, a1, a2, a3;
    {
        ushort4 u = *(const ushort4*)(h1p + (size_t)v * 256 + c4);  // self-loop
        a0 = bf2f(u.x); a1 = bf2f(u.y); a2 = bf2f(u.z); a3 = bf2f(u.w);
    }
    const int e0 = rowp[v], e1 = rowp[v + 1];
    int e = e0;
    for (; e + 4 <= e1; e += 4) {
        int sa = col[e], sb = col[e + 1], sc = col[e + 2], sd = col[e + 3];
        ushort4 ua = *(const ushort4*)(h1p + (size_t)sa * 256 + c4);
        ushort4 ub = *(const ushort4*)(h1p + (size_t)sb * 256 + c4);
        ushort4 uc = *(const ushort4*)(h1p + (size_t)sc * 256 + c4);
        ushort4 ud = *(const ushort4*)(h1p + (size_t)sd * 256 + c4);
        a0 += bf2f(ua.x) + bf2f(ub.x) + bf2f(uc.x) + bf2f(ud.x);
        a1 += bf2f(ua.y) + bf2f(ub.y) + bf2f(uc.y) + bf2f(ud.y);
        a2 += bf2f(ua.z) + bf2f(ub.z) + bf2f(uc.z) + bf2f(ud.z);
        a3 += bf2f(ua.w) + bf2f(ub.w) + bf2f(uc.w) + bf2f(ud.w);
    }
    for (; e < e1; e++) {
        int s = col[e];
        ushort4 u = *(const ushort4*)(h1p + (size_t)s * 256 + c4);
        a0 += bf2f(u.x); a1 += bf2f(u.y); a2 += bf2f(u.z); a3 += bf2f(u.w);
    }
    const float dv = dinv[v];
    float r0 = fmaxf(fmaf(dv, a0, b1[c4 + 0]), 0.f);
    float r1 = fmaxf(fmaf(dv, a1, b1[c4 + 1]), 0.f);
    float r2 = fmaxf(fmaf(dv, a2, b1[c4 + 2]), 0.f);
    float r3 = fmaxf(fmaf(dv, a3, b1[c4 + 3]), 0.f);
    ushort4 o;
    o.x = f2bf(r0); o.y = f2bf(r1); o.z = f2bf(r2); o.w = f2bf(r3);
    *(ushort4*)(h2 + (size_t)v * 256 + c4) = o;
}

// ---------------- aggregation, layer 2 (40 feats) + bias + log_softmax ----------------
__global__ __launch_bounds__(256) void k_agg2(const short* __restrict__ zp,
                                              const int* __restrict__ rowp,
                                              const int* __restrict__ col,
                                              const float* __restrict__ dinv,
                                              const float* __restrict__ b2,
                                              float* __restrict__ out, int n) {
    const int w = threadIdx.x >> 6, lane = threadIdx.x & 63;
    const int v = blockIdx.x * 4 + w;
    if (v >= n) return;
    const bool act = lane < 40;
    const int li = act ? lane : 0;
    float acc = act ? bf2f((unsigned short)zp[(size_t)v * 40 + li]) : 0.f;  // self-loop
    const int e0 = rowp[v], e1 = rowp[v + 1];
    int e = e0;
    for (; e + 4 <= e1; e += 4) {
        int sa = col[e], sb = col[e + 1], sc = col[e + 2], sd = col[e + 3];
        float fa = bf2f((unsigned short)zp[(size_t)sa * 40 + li]);
        float fb = bf2f((unsigned short)zp[(size_t)sb * 40 + li]);
        float fc = bf2f((unsigned short)zp[(size_t)sc * 40 + li]);
        float fd = bf2f((unsigned short)zp[(size_t)sd * 40 + li]);
        if (act) acc += fa + fb + fc + fd;
    }
    for (; e < e1; e++) {
        float f = bf2f((unsigned short)zp[(size_t)col[e] * 40 + li]);
        if (act) acc += f;
    }
    float logit = act ? fmaf(dinv[v], acc, b2[li]) : -1e30f;
    float m = logit;
    for (int off = 32; off; off >>= 1) m = fmaxf(m, __shfl_xor(m, off));
    float ex = act ? expf(logit - m) : 0.f;
    float ssum = ex;
    for (int off = 32; off; off >>= 1) ssum += __shfl_xor(ssum, off);
    if (act) out[(size_t)v * 40 + lane] = logit - m - logf(ssum);
}

extern "C" void kernel_launch(void* const* d_in, const int* in_sizes, int n_in,
                              void* d_out, int out_size, void* d_ws, size_t ws_size,
                              hipStream_t stream) {
    const float* x  = (const float*)d_in[0];
    const float* W1 = (const float*)d_in[1];
    const float* b1 = (const float*)d_in[2];
    const float* W2 = (const float*)d_in[3];
    const float* b2 = (const float*)d_in[4];
    const int*   ei = (const int*)d_in[5];
    float* out = (float*)d_out;

    const int FIN = 512, H = 256, C = 40;
    const int n = in_sizes[0] / FIN;   // 100000
    const int E = in_sizes[5] / 2;     // 3200000
    const int nbuck = (n + 127) >> 7;  // 782

    auto align_up = [](size_t v) { return (v + 255) & ~(size_t)255; };
    char* base = (char*)d_ws;
    size_t off = 0;
    short* x_bf  = (short*)(base + off); off += align_up((size_t)n * FIN * 2);  // reused as h2
    short* h1p   = (short*)(base + off); off += align_up((size_t)n * H * 2);    // reused as zp
    float* dinv  = (float*)(base + off); off += align_up((size_t)n * 4);
    int* rowp    = (int*)(base + off);   off += align_up((size_t)(n + 1) * 4);
    int* colarr  = (int*)(base + off);   off += align_up((size_t)E * 4);
    int* packed  = (int*)(base + off);   off += align_up((size_t)E * 4);
    short* W1t   = (short*)(base + off); off += align_up((size_t)H * FIN * 2);
    short* W2t   = (short*)(base + off); off += align_up((size_t)64 * H * 2);
    int* bcnt    = (int*)(base + off);   off += align_up((size_t)(nbuck + 1) * 4);
    int* bbase   = (int*)(base + off);   off += align_up((size_t)(nbuck + 1) * 4);
    int* bcur    = (int*)(base + off);   off += align_up((size_t)nbuck * 4);
    short* h2 = x_bf;   // layer-1 output (after x_bf consumed by gemm1)
    short* zp = h1p;    // layer-2 scaled logits (after h1p consumed by agg1)

    const int* srcp = ei;
    const int* dstp = ei + E;

    hipMemsetAsync(bcnt, 0, (size_t)(nbuck + 1) * 4, stream);
    hipMemsetAsync(W2t, 0, (size_t)64 * H * 2, stream);

    // CSR build (bucketed, L2-friendly)
    k_bhist<<<256, 256, 0, stream>>>(dstp, E, bcnt, nbuck);
    k_bscan<<<1, 1024, 0, stream>>>(bcnt, bbase, bcur, nbuck);
    k_bscatter<<<(E + 8191) / 8192, 256, 0, stream>>>(srcp, dstp, E, bcur, packed, nbuck);
    k_bcsr<<<nbuck, 256, 0, stream>>>(packed, bbase, rowp, colarr, dinv, n, E);

    // dtype conversion
    int n4 = n * (FIN / 4);
    k_cvt_x<<<(n4 + 255) / 256, 256, 0, stream>>>((const float4*)x, (ushort4*)x_bf, n4);
    k_cvt_wt<<<(FIN * H + 255) / 256, 256, 0, stream>>>(W1, W1t, FIN, H, FIN);
    k_cvt_wt<<<(H * C + 255) / 256, 256, 0, stream>>>(W2, W2t, H, C, H);

    // layer 1
    dim3 g1((n + 127) / 128, H / 128);
    k_gemm_bt<4><<<g1, 256, 0, stream>>>(x_bf, W1t, dinv, h1p, n, FIN, H, H);
    k_agg1<<<(n + 3) / 4, 256, 0, stream>>>(h1p, rowp, colarr, dinv, b1, h2, n);
    // layer 2
    dim3 g2((n + 127) / 128, 1);
    k_gemm_bt<2><<<g2, 256, 0, stream>>>(h2, W2t, dinv, zp, n, H, C, C);
    k_agg2<<<(n + 3) / 4, 256, 0, stream>>>(zp, rowp, colarr, dinv, b2, out, n);
}